// Round 10
// baseline (32.881 us; speedup 1.0000x reference)
//
#include <hip/hip_runtime.h>

typedef float f32x2 __attribute__((ext_vector_type(2)));

#define NPTS 4096
#define BATCH 8
#define BLK 256
#define P 8                               // own points per thread
#define CHUNK 256                         // staged points per chunk (== BLK)
#define NSLOT 16                          // chunks -> partial slots
#define OWN_PER_BLK (BLK * P)             // 2048
#define OWN_BLKS (NPTS / OWN_PER_BLK)     // 2 per batch
#define BLOCKS_PER_PASS (BATCH * OWN_BLKS * NSLOT)   // 256
#define TOTAL_BLOCKS (2 * BLOCKS_PER_PASS)           // 512 = 2 blocks/CU
#define HALF_OWN (BATCH * NPTS)           // 32768
#define TOTAL_OWN (2 * HALF_OWN)          // 65536
#define COMBINE_BLOCKS (TOTAL_OWN / BLK)  // 256

// Forced packed-fp32 FMA: d = a*b + c on both lanes (VOP3P, 1 instr).
static __device__ __forceinline__ f32x2 pkfma(f32x2 a, f32x2 b, f32x2 c) {
    f32x2 d;
    asm("v_pk_fma_f32 %0, %1, %2, %3" : "=v"(d) : "v"(a), "v"(b), "v"(c));
    return d;
}

// LDS chunk layout: pairs of staged points, SoA within the pair:
//   s4[2i]   = (q0x, q1x, q0y, q1y)
//   s4[2i+1] = (q0z, q1z, q0w, q1w)     (components prescaled: -2*q, ||q||^2)
// Inner loop per pair-of-staged per own point: 3 v_pk_fma_f32 + 1 v_min3_f32.
// D = ||p||^2 + (||q||^2 - 2 p.q); ||p||^2 added at epilogue.
__global__ __launch_bounds__(BLK, 2) void chamfer_partial_kernel(
    const float* __restrict__ pred,   // [B,3,N]
    const float* __restrict__ gt,     // [B,M,3]
    float* __restrict__ partial)      // [NSLOT][TOTAL_OWN]
{
    __shared__ float4 s4[2 * (CHUNK / 2)];   // 4 KB

    const int bid  = blockIdx.x;
    const int pass = bid / BLOCKS_PER_PASS;
    int r = bid - pass * BLOCKS_PER_PASS;
    const int c = r % NSLOT;
    r /= NSLOT;
    const int b = r / OWN_BLKS;
    const int j = r - b * OWN_BLKS;
    const int t = threadIdx.x;

    const float* p = pred + (size_t)b * 3 * NPTS;
    const float* g = gt   + (size_t)b * NPTS * 3;

    // Stage this chunk in paired-SoA layout (1 staged point per thread).
    {
        float qx, qy, qz;
        int i = c * CHUNK + t;
        if (pass == 0) { qx = g[i * 3 + 0]; qy = g[i * 3 + 1]; qz = g[i * 3 + 2]; }
        else           { qx = p[i]; qy = p[NPTS + i]; qz = p[2 * NPTS + i]; }
        float w = fmaf(qx, qx, fmaf(qy, qy, qz * qz));
        float* sf = (float*)s4;
        int base = (t >> 1) * 8, h = t & 1;
        sf[base + 0 + h] = -2.f * qx;
        sf[base + 2 + h] = -2.f * qy;
        sf[base + 4 + h] = -2.f * qz;
        sf[base + 6 + h] = w;
    }

    // Own points: 8 per thread; splat coords into f32x2 once (loop-invariant).
    f32x2 X2[P], Y2[P], Z2[P];
    float n2[P];
    #pragma unroll
    for (int k = 0; k < P; ++k) {
        int idx = j * OWN_PER_BLK + k * BLK + t;
        float x, y, z;
        if (pass == 0) { x = p[idx]; y = p[NPTS + idx]; z = p[2 * NPTS + idx]; }
        else           { x = g[idx * 3 + 0]; y = g[idx * 3 + 1]; z = g[idx * 3 + 2]; }
        X2[k].x = x; X2[k].y = x;
        Y2[k].x = y; Y2[k].y = y;
        Z2[k].x = z; Z2[k].y = z;
        n2[k] = fmaf(x, x, fmaf(y, y, z * z));
    }
    __syncthreads();

    float acc[P];
    #pragma unroll
    for (int k = 0; k < P; ++k) acc[k] = 3.4e38f;

    #pragma unroll 4
    for (int i = 0; i < CHUNK / 2; ++i) {
        float4 h0 = s4[2 * i + 0];        // (q0x,q1x,q0y,q1y) broadcast b128
        float4 h1 = s4[2 * i + 1];        // (q0z,q1z,q0w,q1w)
        f32x2 xx; xx.x = h0.x; xx.y = h0.y;
        f32x2 yy; yy.x = h0.z; yy.y = h0.w;
        f32x2 zz; zz.x = h1.x; zz.y = h1.y;
        f32x2 ww; ww.x = h1.z; ww.y = h1.w;
        #pragma unroll
        for (int k = 0; k < P; ++k) {
            f32x2 d = pkfma(xx, X2[k], pkfma(yy, Y2[k], pkfma(zz, Z2[k], ww)));
            acc[k] = fminf(fminf(d.x, d.y), acc[k]);   // -> v_min3_f32
        }
    }

    // Epilogue: add ||p||^2 and store one partial per own point.
    #pragma unroll
    for (int k = 0; k < P; ++k) {
        int idx = j * OWN_PER_BLK + k * BLK + t;
        int o = pass * HALF_OWN + b * NPTS + idx;
        partial[(size_t)c * TOTAL_OWN + o] = n2[k] + acc[k];
    }
}

// Min over the 16 slots per own point, then deterministic block partial sums.
__global__ __launch_bounds__(BLK) void chamfer_combine_kernel(
    const float* __restrict__ partial, float* __restrict__ bsum)
{
    __shared__ float red[BLK / 64];
    const int t = threadIdx.x;
    const int o = blockIdx.x * BLK + t;
    float v = 3.4e38f;
    #pragma unroll
    for (int cc = 0; cc < NSLOT; ++cc)
        v = fminf(v, partial[(size_t)cc * TOTAL_OWN + o]);
    #pragma unroll
    for (int off = 32; off > 0; off >>= 1)
        v += __shfl_down(v, off, 64);
    if ((t & 63) == 0) red[t >> 6] = v;
    __syncthreads();
    if (t == 0) bsum[blockIdx.x] = red[0] + red[1] + red[2] + red[3];
}

__global__ __launch_bounds__(COMBINE_BLOCKS) void chamfer_final_kernel(
    const float* __restrict__ bsum, float* __restrict__ out)
{
    __shared__ float red[COMBINE_BLOCKS / 64];
    const int t = threadIdx.x;
    float v = bsum[t];
    #pragma unroll
    for (int off = 32; off > 0; off >>= 1)
        v += __shfl_down(v, off, 64);
    if ((t & 63) == 0) red[t >> 6] = v;
    __syncthreads();
    if (t == 0) {
        float s = 0.f;
        #pragma unroll
        for (int w = 0; w < COMBINE_BLOCKS / 64; ++w) s += red[w];
        // loss = (sum of all mins) / (NPTS * BATCH)   (N == M)
        out[0] = s * (1.0f / ((float)NPTS * (float)BATCH));
    }
}

extern "C" void kernel_launch(void* const* d_in, const int* in_sizes, int n_in,
                              void* d_out, int out_size, void* d_ws, size_t ws_size,
                              hipStream_t stream) {
    const float* pred = (const float*)d_in[0];  // [8,3,4096]
    const float* gt   = (const float*)d_in[1];  // [8,4096,3]
    float* out = (float*)d_out;

    float* partial = (float*)d_ws;                                  // 16*65536 floats = 4 MB
    float* bsum    = partial + (size_t)NSLOT * TOTAL_OWN;           // 256 floats

    chamfer_partial_kernel<<<TOTAL_BLOCKS, BLK, 0, stream>>>(pred, gt, partial);
    chamfer_combine_kernel<<<COMBINE_BLOCKS, BLK, 0, stream>>>(partial, bsum);
    chamfer_final_kernel<<<1, COMBINE_BLOCKS, 0, stream>>>(bsum, out);
}